// Round 9
// baseline (372.823 us; speedup 1.0000x reference)
//
#include <hip/hip_runtime.h>

// MHA forward: x(2,2048,2048) fp32, Wq/Wk/Wv/Wo (2048,2048) fp32 -> out fp32.
// R12: attn occupancy 2->4 waves/SIMD. KVBLK=32 dbuf (36 KB LDS -> 4
//      blocks/CU), grid 1024 = one 64-row q-tile per block with 4-round
//      balanced qt schedule {31-u, u, 23-u, 8+u} (132 iters per CU uniform).
//      P pack: one cvt_pk per reg -> [16][4][4-u32] chunk-XOR layout; sigma
//      preserved on 32-blocks so PV reads stay b128. Staging addresses
//      strength-reduced to 4 incremented pointers. launch_bounds(256,4).
//      GEMMs (BN=192 ring-2, sigma-V epilogue) and cvt unchanged.

#define SEQ 2048
#define DMODEL 2048
#define NH 16
#define HD 128

typedef __attribute__((ext_vector_type(8))) short bf16x8;  // 8 bf16 = 4 VGPRs
typedef __attribute__((ext_vector_type(4))) float f32x4;

__device__ __forceinline__ unsigned short f2bf(float f) {  // RNE fp32->bf16
  unsigned int u = __float_as_uint(f);
  u += 0x7fffu + ((u >> 16) & 1u);
  return (unsigned short)(u >> 16);
}

__device__ __forceinline__ void g2l16(const void* g, void* l) {
  __builtin_amdgcn_global_load_lds((const __attribute__((address_space(1))) void*)g,
                                   (__attribute__((address_space(3))) void*)l,
                                   16, 0, 0);
}

__device__ __forceinline__ f32x4 mfma16(bf16x8 a, bf16x8 b, f32x4 c) {
  return __builtin_amdgcn_mfma_f32_16x16x32_bf16(a, b, c, 0, 0, 0);
}

template <int CTRL>
__device__ __forceinline__ float dpp_ror(float v) {
  return __int_as_float(__builtin_amdgcn_mov_dpp(__float_as_int(v), CTRL, 0xf, 0xf, false));
}
__device__ __forceinline__ float red_max16(float v) {
  v = fmaxf(v, dpp_ror<0x128>(v));
  v = fmaxf(v, dpp_ror<0x124>(v));
  v = fmaxf(v, dpp_ror<0x122>(v));
  v = fmaxf(v, dpp_ror<0x121>(v));
  return v;
}
__device__ __forceinline__ float red_sum16(float v) {
  v += dpp_ror<0x128>(v);
  v += dpp_ror<0x124>(v);
  v += dpp_ror<0x122>(v);
  v += dpp_ror<0x121>(v);
  return v;
}

// one launch: converts x + all four weights to bf16, permutes Wq/Wk rows
// within-head (RoPE pairs -> adjacent 16-col fragments), fills rope table.
__global__ __launch_bounds__(256) void cvt_all(const float* __restrict__ x,
                                               const float* __restrict__ wq,
                                               const float* __restrict__ wk,
                                               const float* __restrict__ wv,
                                               const float* __restrict__ wo,
                                               unsigned short* __restrict__ dst0,
                                               float2* __restrict__ rtab) {
  const int b = blockIdx.x;
  if (b >= 24576) {  // rope cos/sin table: 2048 x 64
    const int idx = (b - 24576) * 256 + threadIdx.x;  // [0, 131072)
    const int s = idx >> 6, d = idx & 63;
    float sn, cs;
    sincosf((float)s * exp2f(-0.20762050593046f * (float)d), &sn, &cs);
    rtab[idx] = make_float2(cs, sn);
    return;
  }
  const float* src;
  unsigned short* dst;
  int idx, r = -1;
  if (b < 8192) {  // x: 2097152 float4's
    src = x; dst = dst0; idx = b * 256 + threadIdx.x;
  } else {
    r = (b - 8192) >> 12;  // 4096 blocks per weight
    src = (r == 0) ? wq : (r == 1) ? wk : (r == 2) ? wv : wo;
    dst = dst0 + (size_t)2 * SEQ * DMODEL + (size_t)r * DMODEL * DMODEL;
    idx = ((b - 8192) & 4095) * 256 + threadIdx.x;
  }
  const float4 v = ((const float4*)src)[idx];
  ushort4 o;
  o.x = f2bf(v.x); o.y = f2bf(v.y); o.z = f2bf(v.z); o.w = f2bf(v.w);
  int widx = idx;
  if (r == 0 || r == 1) {  // permute Wq/Wk output-feature rows within head
    const int row = idx >> 9, col = idx & 511;
    const int o_ = row & 127;
    const int e = (((o_ >> 4) & 3) << 5) | (((o_ >> 6) & 1) << 4) | (o_ & 15);
    widx = (((row & ~127) | e) << 9) | col;
  }
  ((ushort4*)dst)[widx] = o;
}

// ---------------------------------------------------------------------------
// Pipelined GEMM core: C[m,n] = sum_k A[m,k]*B[n,k].
// BM=256, BN=192(MODE0)/128(MODE1), BK=64. 512 threads = 8 waves (4M x 2N).
// Ring-2 LDS; stage t+1 interleaved with compute of t; vmcnt(0)+barrier per
// tile. Natural dim3 grid (gridDim.x%8==0 -> B panels XCD-L2-resident).
// MODE 0: fused QKV; V keys are stored sigma-permuted within 64-blocks so the
// attention kernel's packed-P PV MFMA sees a consistent k-order.
// ---------------------------------------------------------------------------
template <int MODE>
__global__ __launch_bounds__(512, 2) void gemm_pipe(
    const unsigned short* __restrict__ A,
    const unsigned short* __restrict__ B,
    unsigned short* __restrict__ obf,   // MODE0: qb (kb=+NX, vb=+2NX)
    float* __restrict__ of32,           // MODE1: output
    const float2* __restrict__ rtab) {
  constexpr int BN = (MODE == 0) ? 192 : 128;
  constexpr int NTW = BN / 32;            // B frags per wave: 6 / 4
  constexpr int TILE = (256 + BN) * 64;   // shorts per ring buffer
  constexpr int NU = 32 + BN / 8;         // staging units: 56 / 48
  constexpr int UPW = NU / 8;             // units per wave: 7 / 6
  __shared__ unsigned short lds[2 * TILE];
  const int nb = blockIdx.x, mb = blockIdx.y;
  const int M0 = mb * 256;
  const int t = threadIdx.x;
  const int w = t >> 6, lane = t & 63, l15 = lane & 15, quad = lane >> 4;
  const int g = lane >> 3, j = lane & 7;
  const int wm = w >> 1, wn = w & 1;

  const unsigned short* Abase = A + (size_t)M0 * DMODEL;
  const unsigned short* Bbase = B + (size_t)nb * BN * DMODEL;

  f32x4 acc[4][NTW] = {};

  auto stage = [&](int buf, int k0, int i0, int i1) {
#pragma unroll
    for (int i = i0; i < i1; ++i) {
      const int u = w * UPW + i;
      if (u < 32) {
        g2l16(Abase + (size_t)(u * 8 + g) * DMODEL + k0 + ((j ^ g) << 3),
              &lds[buf * TILE + u * 512]);
      } else {
        g2l16(Bbase + (size_t)((u - 32) * 8 + g) * DMODEL + k0 + ((j ^ g) << 3),
              &lds[buf * TILE + 16384 + (u - 32) * 512]);
      }
    }
  };

  auto comp = [&](int buf, int kc) {
    const int c = kc * 4 + quad;
    const unsigned short* As_ = &lds[buf * TILE];
    const unsigned short* Bs_ = &lds[buf * TILE + 16384];
    bf16x8 af[4], bv[NTW];
#pragma unroll
    for (int mt = 0; mt < 4; ++mt) {
      const int m = wm * 64 + mt * 16 + l15;
      af[mt] = *(const bf16x8*)&As_[m * 64 + ((c ^ (m & 7)) << 3)];
    }
#pragma unroll
    for (int nt = 0; nt < NTW; ++nt) {
      const int n = wn * (BN / 2) + nt * 16 + l15;
      bv[nt] = *(const bf16x8*)&Bs_[n * 64 + ((c ^ (n & 7)) << 3)];
    }
#pragma unroll
    for (int nt = 0; nt < NTW; ++nt)
#pragma unroll
      for (int mt = 0; mt < 4; ++mt)
        acc[mt][nt] = mfma16(af[mt], bv[nt], acc[mt][nt]);
  };

  stage(0, 0, 0, UPW);
  asm volatile("s_waitcnt vmcnt(0)\n\ts_barrier" ::: "memory");

  int buf = 0;
  for (int tt = 0; tt < 32; ++tt) {
    const bool ps = (tt < 31);
    if (ps) stage(buf ^ 1, tt * 64 + 64, 0, UPW / 2);
    comp(buf, 0);
    if (ps) stage(buf ^ 1, tt * 64 + 64, UPW / 2, UPW);
    comp(buf, 1);
    if (ps) {
      asm volatile("s_waitcnt vmcnt(0)\n\ts_barrier" ::: "memory");
      buf ^= 1;
    }
  }

  // Epilogue. C/D layout: col = l15 (N side), row = quad*4 + reg (M side).
  if (MODE == 0) {
    const size_t NX = (size_t)2 * SEQ * DMODEL;
#pragma unroll
    for (int pp = 0; pp < NTW / 2; ++pp) {
      const int colb = nb * BN + wn * (BN / 2) + pp * 32;  // 32-aligned
      const int z = colb >> 11;          // 0:Q 1:K 2:V
      const int zc = colb & 2047;
      const int h = zc >> 7;             // head
      const int e0 = zc & 127;           // in-head col base (0/32/64/96)
      if (z < 2) {
        const float qscale = (z == 0) ? 0.1275174356f : 1.0f;
        unsigned short* O = obf + (size_t)z * NX;
        const int rt = (e0 >> 5) * 16 + l15;  // rope dim q*16 + r
#pragma unroll
        for (int mt = 0; mt < 4; ++mt)
#pragma unroll
          for (int reg = 0; reg < 4; ++reg) {
            const int m = M0 + wm * 64 + mt * 16 + quad * 4 + reg;
            const int bb = m >> 11, s = m & 2047;
            unsigned short* ob = O + ((size_t)(bb * NH + h) * SEQ + s) * HD;
            const float2 cs = rtab[s * 64 + rt];
            const float x1 = acc[mt][2 * pp][reg], x2 = acc[mt][2 * pp + 1][reg];
            ob[e0 + l15] = f2bf((x1 * cs.x - x2 * cs.y) * qscale);
            ob[e0 + 16 + l15] = f2bf((x2 * cs.x + x1 * cs.y) * qscale);
          }
      } else {
        // V stored transposed (B,H,hd,S) with seq index sigma-permuted within
        // each 64-block: spos = (k>>5)*32 + ((k&15)>>2)*8 + (k&3)*2 + ((k>>4)&1)
        // (preserves 32-block halves) so attn's packed-P PV reads a
        // consistent k-order (see attn_kernel).
        unsigned short* Vb0 = obf + 2 * NX + (size_t)h * HD * SEQ;
#pragma unroll
        for (int q2 = 0; q2 < 2; ++q2) {
          const int d = e0 + q2 * 16 + l15;
#pragma unroll
          for (int mt = 0; mt < 4; ++mt)
#pragma unroll
            for (int reg = 0; reg < 4; ++reg) {
              const int m = M0 + wm * 64 + mt * 16 + quad * 4 + reg;
              const int bb = m >> 11, s = m & 2047;
              const int spos = (s & ~63) |
                               ((mt >> 1) * 32 + quad * 8 + reg * 2 + (mt & 1));
              unsigned short* ob = Vb0 + (size_t)bb * NH * HD * SEQ;
              ob[(size_t)d * SEQ + spos] = f2bf(acc[mt][2 * pp + q2][reg]);
            }
        }
      }
    }
  } else {
#pragma unroll
    for (int mt = 0; mt < 4; ++mt)
#pragma unroll
      for (int reg = 0; reg < 4; ++reg) {
        const int m = M0 + wm * 64 + mt * 16 + quad * 4 + reg;
#pragma unroll
        for (int nt = 0; nt < NTW; ++nt)
          of32[(size_t)m * DMODEL + nb * BN + wn * (BN / 2) + nt * 16 + l15] =
              acc[mt][nt][reg];
      }
  }
}

// ---------------------------------------------------------------------------
// Flash attention, causal. QBLK=64 (4 waves x 16 rows), KVBLK=32, dbuf K/V.
// Grid 1024 = one q-tile per block, 4 rounds of 256; qt schedule per round
// {31-u, u, 23-u, 8+u} -> any CU receiving one block per round gets exactly
// 132 iterations (uniform). 36 KB LDS -> 4 blocks/CU = 4 waves/SIMD.
// Per iter: stage(kt+1 via incremented pointers) ; QK^T (2 tiles) ; softmax ;
// P: one cvt_pk per reg -> [16 rows][4 chunks^row][4 u32] (sigma-consistent);
// PV: P as b128 A-frag + V b128 (slot = quad ^ ((d>>1)&3), 2-way banks);
// vmcnt(0)+barrier. bh = gid&31 keeps K/V XCD-local.
// ---------------------------------------------------------------------------
__global__ __launch_bounds__(256, 4) void attn_kernel(const unsigned short* __restrict__ Q,
                                                      const unsigned short* __restrict__ K,
                                                      const unsigned short* __restrict__ Vt,
                                                      unsigned short* __restrict__ Oa) {
  __shared__ unsigned short Ks[2][32 * 128];  // 2 x 8 KB
  __shared__ unsigned short Vs[2][128 * 32];  // 2 x 8 KB
  __shared__ unsigned short Ps[4][512];       // 4 x 1 KB wave-private P
  const int gid = blockIdx.x;
  const int r = gid >> 8, c = gid & 255;
  const int bh = c & 31, u = c >> 5;
  const int qt = (r == 0) ? 31 - u : (r == 1) ? u : (r == 2) ? 23 - u : 8 + u;
  const unsigned short* Qb = Q + (size_t)bh * SEQ * HD;
  const int t = threadIdx.x;
  const int w = t >> 6, lane = t & 63, l15 = lane & 15, quad = lane >> 4;
  const int b = bh >> 4, h = bh & 15;

  // staging source pointers (per-thread, advanced by constant stride per tile)
  const int uk0 = t, uk1 = 256 + t;
  const int k0key = uk0 >> 4, k0cs = uk0 & 15;
  const int k1key = uk1 >> 4, k1cs = uk1 & 15;
  const unsigned short* kp0 = K + (size_t)bh * SEQ * HD +
                              (size_t)k0key * HD + (((k0cs ^ (k0key & 7)) & 15) << 3);
  const unsigned short* kp1 = K + (size_t)bh * SEQ * HD +
                              (size_t)k1key * HD + (((k1cs ^ (k1key & 7)) & 15) << 3);
  const int v0d = uk0 >> 2, v0cs = uk0 & 3;
  const int v1d = uk1 >> 2, v1cs = uk1 & 3;
  const unsigned short* vp0 = Vt + (size_t)bh * HD * SEQ +
                              (size_t)v0d * SEQ + ((v0cs ^ ((v0d >> 1) & 3)) << 3);
  const unsigned short* vp1 = Vt + (size_t)bh * HD * SEQ +
                              (size_t)v1d * SEQ + ((v1cs ^ ((v1d >> 1) & 3)) << 3);

  auto stage = [&](int sb) {  // stage next K/V tile; advance pointers
    g2l16(kp0, &Ks[sb][(w * 64) * 8]);
    g2l16(kp1, &Ks[sb][(256 + w * 64) * 8]);
    g2l16(vp0, &Vs[sb][(w * 64) * 8]);
    g2l16(vp1, &Vs[sb][(256 + w * 64) * 8]);
    kp0 += 32 * HD; kp1 += 32 * HD; vp0 += 32; vp1 += 32;
  };

  // Q fragments: A-layout row = l15, k(hd) = ch*32 + quad*8
  bf16x8 qf[4];
#pragma unroll
  for (int ch = 0; ch < 4; ++ch)
    qf[ch] = *(const bf16x8*)(Qb + (size_t)(qt * 64 + w * 16 + l15) * HD +
                              ch * 32 + quad * 8);

  f32x4 o[8] = {};
  float mrow[4], lrow[4];
#pragma unroll
  for (int reg = 0; reg < 4; ++reg) { mrow[reg] = -1e30f; lrow[reg] = 0.f; }

  const int ktmax = 2 * qt + 1;
  stage(0);
  asm volatile("s_waitcnt vmcnt(0)\n\ts_barrier" ::: "memory");
  int buf = 0;

  for (int kt = 0; kt <= ktmax; ++kt) {
    if (kt < ktmax) stage(buf ^ 1);  // prefetch next tile

    const bool dz = (kt >= 2 * qt);  // diagonal zone
    const int ntm = dz ? ((qt * 64 + w * 16 + 15 - kt * 32) >> 4) : 1;
    if (ntm >= 0) {
      // S = Q K^T (Q pre-scaled by log2e/sqrt(hd))
      f32x4 s[2] = {};
      __builtin_amdgcn_s_setprio(1);
#pragma unroll
      for (int ch = 0; ch < 4; ++ch) {
        const int cc = ch * 4 + quad;
#pragma unroll
        for (int nt = 0; nt < 2; ++nt) {
          if (nt <= ntm) {
            const int n = nt * 16 + l15;
            const bf16x8 bv = *(const bf16x8*)&Ks[buf][n * 128 + ((cc ^ (n & 7)) << 3)];
            s[nt] = mfma16(qf[ch], bv, s[nt]);
          }
        }
      }
      __builtin_amdgcn_s_setprio(0);

      if (dz) {  // causal mask
#pragma unroll
        for (int nt = 0; nt < 2; ++nt)
#pragma unroll
          for (int reg = 0; reg < 4; ++reg) {
            const int rr = qt * 64 + w * 16 + quad * 4 + reg;
            const int cc = kt * 32 + nt * 16 + l15;
            if (cc > rr) s[nt][reg] = -1e30f;
          }
      }

      // online softmax in log2 domain, defer-max rescale (THR=8)
#pragma unroll
      for (int reg = 0; reg < 4; ++reg) {
        float vmax = fmaxf(s[0][reg], s[1][reg]);
        vmax = red_max16(vmax);
        const float mo = mrow[reg];
        float mn = mo;
        if (!__all(vmax <= mo + 8.0f)) {  // wave-uniform branch
          mn = fmaxf(mo, vmax);
          const float alpha = exp2f(mo - mn);
          mrow[reg] = mn;
          lrow[reg] *= alpha;
#pragma unroll
          for (int nt = 0; nt < 8; ++nt) o[nt][reg] *= alpha;
        }
        float rs = 0.f;
#pragma unroll
        for (int nt = 0; nt < 2; ++nt) {
          const float p_ = exp2f(s[nt][reg] - mn);
          s[nt][reg] = p_;
          rs += p_;
        }
        rs = red_sum16(rs);
        lrow[reg] += rs;
      }

      // P pack: u32 = cvt_pk(s[0][reg], s[1][reg]) = keys (l15, l15+16)
      // = sigma-positions (base, base+1), base = (l15>>2)*8 + (l15&3)*2.
      // Layout [row][chunk][word], phys chunk = (l15>>2) ^ (row&3).
      unsigned int* Pw32 = (unsigned int*)Ps[w];
#pragma unroll
      for (int reg = 0; reg < 4; ++reg) {
        unsigned int pu;
        asm("v_cvt_pk_bf16_f32 %0, %1, %2"
            : "=v"(pu)
            : "v"(s[0][reg]), "v"(s[1][reg]));
        Pw32[(quad * 4 + reg) * 16 + (((l15 >> 2) ^ reg) << 2) + (l15 & 3)] = pu;
      }
      asm volatile("" ::: "memory");  // order P writes before P reads

      // O += P V  (V in sigma k-order; A row = l15, k-chunk = quad)
      const bf16x8 pa = *(const bf16x8*)&Ps[w][l15 * 32 + ((quad ^ (l15 & 3)) << 3)];
      __builtin_amdgcn_s_setprio(1);
#pragma unroll
      for (int nt = 0; nt < 8; ++nt) {
        const int d = nt * 16 + l15;
        const bf16x8 vv = *(const bf16x8*)&Vs[buf][d * 32 + ((quad ^ ((d >> 1) & 3)) << 3)];
        o[nt] = mfma16(pa, vv, o[nt]);
      }
      __builtin_amdgcn_s_setprio(0);
    }

    // single barrier per iter: next tile's loads (issued at top) now land.
    asm volatile("s_waitcnt vmcnt(0)\n\ts_barrier" ::: "memory");
    buf ^= 1;
  }

  // epilogue: normalize and store attn output as (B*S, D) bf16
#pragma unroll
  for (int reg = 0; reg < 4; ++reg) {
    const int sq = qt * 64 + w * 16 + quad * 4 + reg;
    const float inv_l = 1.0f / lrow[reg];
    unsigned short* ob = Oa + (size_t)(b * SEQ + sq) * DMODEL + h * HD;
#pragma unroll
    for (int nt = 0; nt < 8; ++nt) ob[nt * 16 + l15] = f2bf(o[nt][reg] * inv_l);
  }
}

extern "C" void kernel_launch(void* const* d_in, const int* in_sizes, int n_in,
                              void* d_out, int out_size, void* d_ws, size_t ws_size,
                              hipStream_t stream) {
  const float* x = (const float*)d_in[0];
  const float* Wq = (const float*)d_in[1];
  const float* Wk = (const float*)d_in[2];
  const float* Wv = (const float*)d_in[3];
  const float* Wo = (const float*)d_in[4];
  float* out = (float*)d_out;

  const size_t NX = (size_t)2 * SEQ * DMODEL;
  const size_t NW = (size_t)DMODEL * DMODEL;
  unsigned short* ws = (unsigned short*)d_ws;
  unsigned short* xb = ws;
  unsigned short* wqb = xb + NX;   // wq/wk/wv contiguous -> fused N=6144 B operand
  unsigned short* wkb = wqb + NW;
  unsigned short* wvb = wkb + NW;
  unsigned short* wob = wvb + NW;
  unsigned short* qb = wob + NW;  // (B,H,S,hd) permuted-hd, rope'd, *log2e/sqrt(hd)
  unsigned short* kb = qb + NX;   // (B,H,S,hd) permuted-hd, rope'd
  unsigned short* vb = kb + NX;   // (B,H,hd,S), seq sigma-permuted per 64-block
  unsigned short* ab = vb + NX;   // (B*S, D)
  float2* rtab = (float2*)(ab + NX);  // 2048 x 64 cos/sin (1 MB)

  cvt_all<<<25088, 256, 0, stream>>>(x, Wq, Wk, Wv, Wo, ws, rtab);
  gemm_pipe<0><<<dim3(32, 16), 512, 0, stream>>>(xb, wqb, qb, nullptr, rtab);
  attn_kernel<<<1024, 256, 0, stream>>>(qb, kb, vb, ab);
  gemm_pipe<1><<<dim3(16, 16), 512, 0, stream>>>(ab, wob, nullptr, out, nullptr);
}

// Round 10
// 356.179 us; speedup vs baseline: 1.0467x; 1.0467x over previous
//
#include <hip/hip_runtime.h>

// MHA forward: x(2,2048,2048) fp32, Wq/Wk/Wv/Wo (2048,2048) fp32 -> out fp32.
// R13: attn = R11 skeleton (QBLK=64, 4 waves, KVBLK=64 dbuf, pairs (pr,31-pr)
//      -> 33 iters uniform, grid 512 = 2 blocks/CU) with SWAPPED QK^T
//      (mfma(K,Q) -> S^T): each lane owns one q-row (q=l15, keys=quad*4+reg
//      +16nt), so the softmax row-reduce is an in-lane tree + 2 shfl_xor
//      (replaces 8 serial dpp-chains/wave/iter). m/l are per-lane scalars;
//      alpha/l redistributed to O-layout (q=quad*4+reg) via __shfl(..,16).
//      P pack: cvt_pk pairs consecutive in-lane keys -> NO sigma-V needed
//      (gemm0 V-epilogue reverted to natural stores). P LDS [16 rows][32 u32]
//      physcol ^= (l15&7)<<2: write 2-way, b128 read conflict-free.
//      GEMMs (BN=192 ring-2) otherwise unchanged; cvt unchanged.

#define SEQ 2048
#define DMODEL 2048
#define NH 16
#define HD 128

typedef __attribute__((ext_vector_type(8))) short bf16x8;  // 8 bf16 = 4 VGPRs
typedef __attribute__((ext_vector_type(4))) float f32x4;

__device__ __forceinline__ unsigned short f2bf(float f) {  // RNE fp32->bf16
  unsigned int u = __float_as_uint(f);
  u += 0x7fffu + ((u >> 16) & 1u);
  return (unsigned short)(u >> 16);
}

__device__ __forceinline__ void g2l16(const void* g, void* l) {
  __builtin_amdgcn_global_load_lds((const __attribute__((address_space(1))) void*)g,
                                   (__attribute__((address_space(3))) void*)l,
                                   16, 0, 0);
}

__device__ __forceinline__ f32x4 mfma16(bf16x8 a, bf16x8 b, f32x4 c) {
  return __builtin_amdgcn_mfma_f32_16x16x32_bf16(a, b, c, 0, 0, 0);
}

// one launch: converts x + all four weights to bf16, permutes Wq/Wk rows
// within-head (RoPE pairs -> adjacent 16-col fragments), fills rope table.
__global__ __launch_bounds__(256) void cvt_all(const float* __restrict__ x,
                                               const float* __restrict__ wq,
                                               const float* __restrict__ wk,
                                               const float* __restrict__ wv,
                                               const float* __restrict__ wo,
                                               unsigned short* __restrict__ dst0,
                                               float2* __restrict__ rtab) {
  const int b = blockIdx.x;
  if (b >= 24576) {  // rope cos/sin table: 2048 x 64
    const int idx = (b - 24576) * 256 + threadIdx.x;  // [0, 131072)
    const int s = idx >> 6, d = idx & 63;
    float sn, cs;
    sincosf((float)s * exp2f(-0.20762050593046f * (float)d), &sn, &cs);
    rtab[idx] = make_float2(cs, sn);
    return;
  }
  const float* src;
  unsigned short* dst;
  int idx, r = -1;
  if (b < 8192) {  // x: 2097152 float4's
    src = x; dst = dst0; idx = b * 256 + threadIdx.x;
  } else {
    r = (b - 8192) >> 12;  // 4096 blocks per weight
    src = (r == 0) ? wq : (r == 1) ? wk : (r == 2) ? wv : wo;
    dst = dst0 + (size_t)2 * SEQ * DMODEL + (size_t)r * DMODEL * DMODEL;
    idx = ((b - 8192) & 4095) * 256 + threadIdx.x;
  }
  const float4 v = ((const float4*)src)[idx];
  ushort4 o;
  o.x = f2bf(v.x); o.y = f2bf(v.y); o.z = f2bf(v.z); o.w = f2bf(v.w);
  int widx = idx;
  if (r == 0 || r == 1) {  // permute Wq/Wk output-feature rows within head
    const int row = idx >> 9, col = idx & 511;
    const int o_ = row & 127;
    const int e = (((o_ >> 4) & 3) << 5) | (((o_ >> 6) & 1) << 4) | (o_ & 15);
    widx = (((row & ~127) | e) << 9) | col;
  }
  ((ushort4*)dst)[widx] = o;
}

// ---------------------------------------------------------------------------
// Pipelined GEMM core: C[m,n] = sum_k A[m,k]*B[n,k].
// BM=256, BN=192(MODE0)/128(MODE1), BK=64. 512 threads = 8 waves (4M x 2N).
// Ring-2 LDS; stage t+1 interleaved with compute of t; vmcnt(0)+barrier per
// tile. Natural dim3 grid (gridDim.x%8==0 -> B panels XCD-L2-resident).
// MODE 0: fused QKV (V stored transposed, natural key order).
// ---------------------------------------------------------------------------
template <int MODE>
__global__ __launch_bounds__(512, 2) void gemm_pipe(
    const unsigned short* __restrict__ A,
    const unsigned short* __restrict__ B,
    unsigned short* __restrict__ obf,   // MODE0: qb (kb=+NX, vb=+2NX)
    float* __restrict__ of32,           // MODE1: output
    const float2* __restrict__ rtab) {
  constexpr int BN = (MODE == 0) ? 192 : 128;
  constexpr int NTW = BN / 32;            // B frags per wave: 6 / 4
  constexpr int TILE = (256 + BN) * 64;   // shorts per ring buffer
  constexpr int NU = 32 + BN / 8;         // staging units: 56 / 48
  constexpr int UPW = NU / 8;             // units per wave: 7 / 6
  __shared__ unsigned short lds[2 * TILE];
  const int nb = blockIdx.x, mb = blockIdx.y;
  const int M0 = mb * 256;
  const int t = threadIdx.x;
  const int w = t >> 6, lane = t & 63, l15 = lane & 15, quad = lane >> 4;
  const int g = lane >> 3, j = lane & 7;
  const int wm = w >> 1, wn = w & 1;

  const unsigned short* Abase = A + (size_t)M0 * DMODEL;
  const unsigned short* Bbase = B + (size_t)nb * BN * DMODEL;

  f32x4 acc[4][NTW] = {};

  auto stage = [&](int buf, int k0, int i0, int i1) {
#pragma unroll
    for (int i = i0; i < i1; ++i) {
      const int u = w * UPW + i;
      if (u < 32) {
        g2l16(Abase + (size_t)(u * 8 + g) * DMODEL + k0 + ((j ^ g) << 3),
              &lds[buf * TILE + u * 512]);
      } else {
        g2l16(Bbase + (size_t)((u - 32) * 8 + g) * DMODEL + k0 + ((j ^ g) << 3),
              &lds[buf * TILE + 16384 + (u - 32) * 512]);
      }
    }
  };

  auto comp = [&](int buf, int kc) {
    const int c = kc * 4 + quad;
    const unsigned short* As_ = &lds[buf * TILE];
    const unsigned short* Bs_ = &lds[buf * TILE + 16384];
    bf16x8 af[4], bv[NTW];
#pragma unroll
    for (int mt = 0; mt < 4; ++mt) {
      const int m = wm * 64 + mt * 16 + l15;
      af[mt] = *(const bf16x8*)&As_[m * 64 + ((c ^ (m & 7)) << 3)];
    }
#pragma unroll
    for (int nt = 0; nt < NTW; ++nt) {
      const int n = wn * (BN / 2) + nt * 16 + l15;
      bv[nt] = *(const bf16x8*)&Bs_[n * 64 + ((c ^ (n & 7)) << 3)];
    }
#pragma unroll
    for (int nt = 0; nt < NTW; ++nt)
#pragma unroll
      for (int mt = 0; mt < 4; ++mt)
        acc[mt][nt] = mfma16(af[mt], bv[nt], acc[mt][nt]);
  };

  stage(0, 0, 0, UPW);
  asm volatile("s_waitcnt vmcnt(0)\n\ts_barrier" ::: "memory");

  int buf = 0;
  for (int tt = 0; tt < 32; ++tt) {
    const bool ps = (tt < 31);
    if (ps) stage(buf ^ 1, tt * 64 + 64, 0, UPW / 2);
    comp(buf, 0);
    if (ps) stage(buf ^ 1, tt * 64 + 64, UPW / 2, UPW);
    comp(buf, 1);
    if (ps) {
      asm volatile("s_waitcnt vmcnt(0)\n\ts_barrier" ::: "memory");
      buf ^= 1;
    }
  }

  // Epilogue. C/D layout: col = l15 (N side), row = quad*4 + reg (M side).
  if (MODE == 0) {
    const size_t NX = (size_t)2 * SEQ * DMODEL;
#pragma unroll
    for (int pp = 0; pp < NTW / 2; ++pp) {
      const int colb = nb * BN + wn * (BN / 2) + pp * 32;  // 32-aligned
      const int z = colb >> 11;          // 0:Q 1:K 2:V
      const int zc = colb & 2047;
      const int h = zc >> 7;             // head
      const int e0 = zc & 127;           // in-head col base (0/32/64/96)
      if (z < 2) {
        const float qscale = (z == 0) ? 0.1275174356f : 1.0f;
        unsigned short* O = obf + (size_t)z * NX;
        const int rt = (e0 >> 5) * 16 + l15;  // rope dim q*16 + r
#pragma unroll
        for (int mt = 0; mt < 4; ++mt)
#pragma unroll
          for (int reg = 0; reg < 4; ++reg) {
            const int m = M0 + wm * 64 + mt * 16 + quad * 4 + reg;
            const int bb = m >> 11, s = m & 2047;
            unsigned short* ob = O + ((size_t)(bb * NH + h) * SEQ + s) * HD;
            const float2 cs = rtab[s * 64 + rt];
            const float x1 = acc[mt][2 * pp][reg], x2 = acc[mt][2 * pp + 1][reg];
            ob[e0 + l15] = f2bf((x1 * cs.x - x2 * cs.y) * qscale);
            ob[e0 + 16 + l15] = f2bf((x2 * cs.x + x1 * cs.y) * qscale);
          }
      } else {
        // V stored transposed: (B,H,hd,S), natural key order
        unsigned short* Vb0 = obf + 2 * NX + (size_t)h * HD * SEQ;
#pragma unroll
        for (int q2 = 0; q2 < 2; ++q2) {
          const int d = e0 + q2 * 16 + l15;
#pragma unroll
          for (int mt = 0; mt < 4; ++mt)
#pragma unroll
            for (int reg = 0; reg < 4; ++reg) {
              const int m = M0 + wm * 64 + mt * 16 + quad * 4 + reg;
              const int bb = m >> 11, s = m & 2047;
              unsigned short* ob = Vb0 + (size_t)bb * NH * HD * SEQ;
              ob[(size_t)d * SEQ + s] = f2bf(acc[mt][2 * pp + q2][reg]);
            }
        }
      }
    }
  } else {
#pragma unroll
    for (int mt = 0; mt < 4; ++mt)
#pragma unroll
      for (int reg = 0; reg < 4; ++reg) {
        const int m = M0 + wm * 64 + mt * 16 + quad * 4 + reg;
#pragma unroll
        for (int nt = 0; nt < NTW; ++nt)
          of32[(size_t)m * DMODEL + nb * BN + wn * (BN / 2) + nt * 16 + l15] =
              acc[mt][nt][reg];
      }
  }
}

// ---------------------------------------------------------------------------
// Flash attention, causal. QBLK=64 (4 waves x 16 rows), KVBLK=64, dbuf K/V.
// Block = one (b,h) x q-tile PAIR (pr, 31-pr): 33 kt-iters/block uniform.
// Grid 512 = 2 blocks/CU (72 KB LDS) -> co-resident blocks overlap stalls.
// SWAPPED QK^T: s[nt] = mfma(K-frag, Q-frag) -> lane holds S[key][q=l15],
// keys = nt*16 + quad*4 + reg. Softmax: in-lane tree + shfl_xor(16,32);
// m/l per-lane scalars (q=l15); alpha/l moved to O-layout (q=quad*4+reg)
// via __shfl(..,16). P: cvt_pk packs consecutive keys -> [16 q][32 u32],
// physcol = col ^ ((l15&7)<<2) (write 2-way, b128 read conflict-free).
// PV: A=P (row=l15=q), B=V natural keys. vmcnt(0)+barrier per iter.
// ---------------------------------------------------------------------------
__global__ __launch_bounds__(256) void attn_kernel(const unsigned short* __restrict__ Q,
                                                   const unsigned short* __restrict__ K,
                                                   const unsigned short* __restrict__ Vt,
                                                   unsigned short* __restrict__ Oa) {
  __shared__ unsigned short Ks[2][64 * 128];  // 2 x 16 KB
  __shared__ unsigned short Vs[2][128 * 64];  // 2 x 16 KB
  __shared__ unsigned short Ps[4][1024];      // 4 x 2 KB wave-private P
  const int gid = blockIdx.x;
  const int bh = gid & 31;   // all 16 pair-blocks of one bh on XCD bh%8
  const int pr = gid >> 5;   // pair index 0..15
  const unsigned short* Qb = Q + (size_t)bh * SEQ * HD;
  const unsigned short* Kb = K + (size_t)bh * SEQ * HD;
  const unsigned short* Vb = Vt + (size_t)bh * HD * SEQ;
  const int t = threadIdx.x;
  const int w = t >> 6, lane = t & 63, l15 = lane & 15, quad = lane >> 4;
  const int h7 = l15 & 7;
  const int b = bh >> 4, h = bh & 15;
  const int uA = w * 64 + lane;  // staging unit base (i*256 added per instr)

  // stage K/V tile kt into buffer sb: 256 threads x 4 instr x 16B per tensor.
  auto stage = [&](int sb, int kt) {
    const unsigned short* Kt = Kb + (size_t)(kt * 64) * HD;
    const unsigned short* Vtk = Vb + kt * 64;
#pragma unroll
    for (int i = 0; i < 4; ++i) {
      const int u = i * 256 + uA;
      const int key = u >> 4, cs = u & 15;
      g2l16(Kt + (size_t)key * HD + ((cs ^ (key & 7)) << 3), &Ks[sb][u * 8]);
    }
#pragma unroll
    for (int i = 0; i < 4; ++i) {
      const int u = i * 256 + uA;
      const int d = u >> 3, cs = u & 7;
      g2l16(Vtk + (size_t)d * SEQ + ((cs ^ (d & 7)) << 3), &Vs[sb][u * 8]);
    }
  };

  for (int half = 0; half < 2; ++half) {
    const int qt = half ? 31 - pr : pr;  // q-tile of 64 rows; kt = 0..qt

    // Q fragments (B-operand): col = q = l15, k(hd) = ch*32 + quad*8
    bf16x8 qf[4];
#pragma unroll
    for (int ch = 0; ch < 4; ++ch)
      qf[ch] = *(const bf16x8*)(Qb + (size_t)(qt * 64 + w * 16 + l15) * HD +
                                ch * 32 + quad * 8);

    f32x4 o[8] = {};
    float m_ = -1e30f, l_ = 0.f;  // per-lane: q-row = w*16 + l15

    stage(0, 0);
    asm volatile("s_waitcnt vmcnt(0)\n\ts_barrier" ::: "memory");
    int buf = 0;

    for (int kt = 0; kt <= qt; ++kt) {
      if (kt < qt) stage(buf ^ 1, kt + 1);  // prefetch next tile

      // Diagonal tile: key-tile nt fully masked iff nt > w.
      const bool diag = (kt == qt);
      const int ntm = diag ? w : 3;

      // S^T = K Q^T: s[nt][reg] = S[key = nt*16+quad*4+reg][q = w*16+l15]
      f32x4 s[4] = {};
      __builtin_amdgcn_s_setprio(1);
#pragma unroll
      for (int ch = 0; ch < 4; ++ch) {
        const int c = ch * 4 + quad;
#pragma unroll
        for (int nt = 0; nt < 4; ++nt) {
          if (nt <= ntm) {
            const int key = nt * 16 + l15;
            const bf16x8 kf = *(const bf16x8*)&Ks[buf][key * 128 + ((c ^ (key & 7)) << 3)];
            s[nt] = mfma16(kf, qf[ch], s[nt]);
          }
        }
      }
      __builtin_amdgcn_s_setprio(0);

      if (diag) {  // causal mask: key > q -> -inf (also covers skipped tiles)
#pragma unroll
        for (int nt = 0; nt < 4; ++nt)
#pragma unroll
          for (int reg = 0; reg < 4; ++reg) {
            const int key = nt * 16 + quad * 4 + reg;
            const int qq = w * 16 + l15;
            if (key > qq) s[nt][reg] = -1e30f;
          }
      }

      // online softmax (log2 domain): in-lane tree + 2 shfl_xor; defer-max.
      float pmax = -1e30f;
#pragma unroll
      for (int nt = 0; nt < 4; ++nt)
        pmax = fmaxf(pmax, fmaxf(fmaxf(s[nt][0], s[nt][1]), fmaxf(s[nt][2], s[nt][3])));
      pmax = fmaxf(pmax, __shfl_xor(pmax, 16));
      pmax = fmaxf(pmax, __shfl_xor(pmax, 32));
      float mn = m_;
      if (!__all(pmax <= m_ + 8.0f)) {  // wave-uniform branch
        mn = fmaxf(m_, pmax);
        const float alpha = exp2f(m_ - mn);
        m_ = mn;
        l_ *= alpha;
        float af[4];
#pragma unroll
        for (int reg = 0; reg < 4; ++reg) af[reg] = __shfl(alpha, quad * 4 + reg, 16);
#pragma unroll
        for (int nt = 0; nt < 8; ++nt)
#pragma unroll
          for (int reg = 0; reg < 4; ++reg) o[nt][reg] *= af[reg];
      }
      float rs = 0.f;
#pragma unroll
      for (int nt = 0; nt < 4; ++nt)
#pragma unroll
        for (int reg = 0; reg < 4; ++reg) {
          const float p_ = exp2f(s[nt][reg] - mn);
          s[nt][reg] = p_;
          rs += p_;
        }
      rs += __shfl_xor(rs, 16);
      rs += __shfl_xor(rs, 32);
      l_ += rs;

      // P pack: cvt_pk pairs consecutive keys (quad*4+2p, +1) for q=l15.
      // Store u32 at [row=l15][physcol = (nt*8+quad*2+p) ^ (h7<<2)].
      unsigned int* Pw32 = (unsigned int*)Ps[w];
#pragma unroll
      for (int nt = 0; nt < 4; ++nt)
#pragma unroll
        for (int p = 0; p < 2; ++p) {
          unsigned int u;
          asm("v_cvt_pk_bf16_f32 %0, %1, %2"
              : "=v"(u)
              : "v"(s[nt][2 * p]), "v"(s[nt][2 * p + 1]));
          Pw32[l15 * 32 + ((nt * 8 + quad * 2 + p) ^ (h7 << 2))] = u;
        }
      asm volatile("" ::: "memory");  // order P writes before P reads

      // O += P V. A = P: row = l15 (q), keys = ch2*32 + quad*8 .. +7
      //           B = V: col = d = nt*16+l15, keys natural.
      const int ch2max = (ntm >= 2) ? 1 : 0;
      __builtin_amdgcn_s_setprio(1);
#pragma unroll
      for (int ch2 = 0; ch2 < 2; ++ch2) {
        if (ch2 <= ch2max) {
          const bf16x8 pa =
              *(const bf16x8*)(Pw32 + l15 * 32 + (((ch2 * 16 + quad * 4) ^ (h7 << 2))));
          const int c = ch2 * 4 + quad;
#pragma unroll
          for (int nt = 0; nt < 8; ++nt) {
            const int d = nt * 16 + l15;
            const bf16x8 vv = *(const bf16x8*)&Vs[buf][d * 64 + ((c ^ (d & 7)) << 3)];
            o[nt] = mfma16(pa, vv, o[nt]);
          }
        }
      }
      __builtin_amdgcn_s_setprio(0);

      // single barrier per iter: next tile's loads (issued at top) now land.
      asm volatile("s_waitcnt vmcnt(0)\n\ts_barrier" ::: "memory");
      buf ^= 1;
    }

    // epilogue: normalize (l in O-layout via shfl) and store as (B*S, D) bf16
    float linv[4];
#pragma unroll
    for (int reg = 0; reg < 4; ++reg)
      linv[reg] = 1.0f / __shfl(l_, quad * 4 + reg, 16);
#pragma unroll
    for (int reg = 0; reg < 4; ++reg) {
      const int sq = qt * 64 + w * 16 + quad * 4 + reg;
      unsigned short* ob = Oa + (size_t)(b * SEQ + sq) * DMODEL + h * HD;
#pragma unroll
      for (int nt = 0; nt < 8; ++nt) ob[nt * 16 + l15] = f2bf(o[nt][reg] * linv[reg]);
    }
  }
}

extern "C" void kernel_launch(void* const* d_in, const int* in_sizes, int n_in,
                              void* d_out, int out_size, void* d_ws, size_t ws_size,
                              hipStream_t stream) {
  const float* x = (const float*)d_in[0];
  const float* Wq = (const float*)d_in[1];
  const float* Wk = (const float*)d_in[2];
  const float* Wv = (const float*)d_in[3];
  const float* Wo = (const float*)d_in[4];
  float* out = (float*)d_out;

  const size_t NX = (size_t)2 * SEQ * DMODEL;
  const size_t NW = (size_t)DMODEL * DMODEL;
  unsigned short* ws = (unsigned short*)d_ws;
  unsigned short* xb = ws;
  unsigned short* wqb = xb + NX;   // wq/wk/wv contiguous -> fused N=6144 B operand
  unsigned short* wkb = wqb + NW;
  unsigned short* wvb = wkb + NW;
  unsigned short* wob = wvb + NW;
  unsigned short* qb = wob + NW;  // (B,H,S,hd) permuted-hd, rope'd, *log2e/sqrt(hd)
  unsigned short* kb = qb + NX;   // (B,H,S,hd) permuted-hd, rope'd
  unsigned short* vb = kb + NX;   // (B,H,hd,S), natural key order
  unsigned short* ab = vb + NX;   // (B*S, D)
  float2* rtab = (float2*)(ab + NX);  // 2048 x 64 cos/sin (1 MB)

  cvt_all<<<25088, 256, 0, stream>>>(x, Wq, Wk, Wv, Wo, ws, rtab);
  gemm_pipe<0><<<dim3(32, 16), 512, 0, stream>>>(xb, wqb, qb, nullptr, rtab);
  attn_kernel<<<512, 256, 0, stream>>>(qb, kb, vb, ab);
  gemm_pipe<1><<<dim3(16, 16), 512, 0, stream>>>(ab, wob, nullptr, out, nullptr);
}